// Round 1
// baseline (2053.224 us; speedup 1.0000x reference)
//
#include <hip/hip_runtime.h>
#include <math.h>

#define D_MODEL 1024
#define NUM_HEADS 16
#define DK 64
#define BATCH 2
#define NSEQ 2048
#define MROWS (BATCH * NSEQ)   // 4096

// ---------------------------------------------------------------------------
// GEMM: C[M,N] = A[M,K] @ W[N,K]^T + bias[N]   (torch Linear semantics)
// fp32 vector-ALU baseline. 64x64 tile, BK=16, 256 threads, 4x4 per thread.
// M=4096,N=1024,K=1024 -> grid (16,64) = 1024 blocks (~4 blocks/CU).
// ---------------------------------------------------------------------------
__global__ __launch_bounds__(256)
void gemm_bt_bias(const float* __restrict__ A, const float* __restrict__ W,
                  const float* __restrict__ bias, float* __restrict__ C,
                  int M, int N, int K)
{
    __shared__ float As[16][64];
    __shared__ float Ws[16][64];
    const int tid  = threadIdx.x;
    const int bm   = blockIdx.y * 64;
    const int bn   = blockIdx.x * 64;
    const int lrow = tid >> 2;          // 0..63
    const int lcol = (tid & 3) << 2;    // 0,4,8,12
    const int ty   = tid >> 4;          // 0..15
    const int tx   = tid & 15;          // 0..15

    float acc[4][4] = {{0.f}};

    for (int k0 = 0; k0 < K; k0 += 16) {
        float4 av = *(const float4*)(A + (size_t)(bm + lrow) * K + k0 + lcol);
        float4 wv = *(const float4*)(W + (size_t)(bn + lrow) * K + k0 + lcol);
        // transposed store: As[k][m]
        As[lcol + 0][lrow] = av.x;
        As[lcol + 1][lrow] = av.y;
        As[lcol + 2][lrow] = av.z;
        As[lcol + 3][lrow] = av.w;
        Ws[lcol + 0][lrow] = wv.x;
        Ws[lcol + 1][lrow] = wv.y;
        Ws[lcol + 2][lrow] = wv.z;
        Ws[lcol + 3][lrow] = wv.w;
        __syncthreads();
#pragma unroll
        for (int kk = 0; kk < 16; ++kk) {
            float4 a4 = *(const float4*)(&As[kk][ty << 2]);
            float4 b4 = *(const float4*)(&Ws[kk][tx << 2]);
            float a[4] = {a4.x, a4.y, a4.z, a4.w};
            float b[4] = {b4.x, b4.y, b4.z, b4.w};
#pragma unroll
            for (int i = 0; i < 4; ++i)
#pragma unroll
                for (int j = 0; j < 4; ++j)
                    acc[i][j] = fmaf(a[i], b[j], acc[i][j]);
        }
        __syncthreads();
    }

    float4 bv = *(const float4*)(bias + bn + (tx << 2));
#pragma unroll
    for (int i = 0; i < 4; ++i) {
        float4 cv;
        cv.x = acc[i][0] + bv.x;
        cv.y = acc[i][1] + bv.y;
        cv.z = acc[i][2] + bv.z;
        cv.w = acc[i][3] + bv.w;
        *(float4*)(C + (size_t)(bm + (ty << 2) + i) * N + bn + (tx << 2)) = cv;
    }
}

// ---------------------------------------------------------------------------
// Flash-style attention, fp32. One block per (b, h, 64-row Q tile).
// K/V tiles of 64 rows staged in LDS; online softmax; O in registers.
// Q/K/V/ctx layout: (B, N, D_MODEL) with head h occupying cols [h*64, h*64+64).
// Scale 1/sqrt(64)=0.125 folded into the Q load.
// ---------------------------------------------------------------------------
__global__ __launch_bounds__(256)
void flash_attn(const float* __restrict__ Q, const float* __restrict__ K,
                const float* __restrict__ V, float* __restrict__ O)
{
    __shared__ float Qs[64][68];
    __shared__ float Ks[64][68];
    __shared__ float Vs[64][68];
    __shared__ float Ss[64][68];
    __shared__ float m_sm[64], l_sm[64], a_sm[64];

    const int tid = threadIdx.x;
    const int q0  = blockIdx.x << 6;
    const int h   = blockIdx.y;
    const int b   = blockIdx.z;
    const size_t hbase = (size_t)b * NSEQ * D_MODEL + (size_t)h * DK;

    const int lr = tid >> 2;           // 0..63  (row within tile)
    const int lc = (tid & 3) << 4;     // 0,16,32,48 (col group of 16)

    {   // load + scale Q tile
        const float* src = Q + hbase + (size_t)(q0 + lr) * D_MODEL + lc;
#pragma unroll
        for (int t = 0; t < 4; ++t) {
            float4 v = ((const float4*)src)[t];
            Qs[lr][lc + t * 4 + 0] = v.x * 0.125f;
            Qs[lr][lc + t * 4 + 1] = v.y * 0.125f;
            Qs[lr][lc + t * 4 + 2] = v.z * 0.125f;
            Qs[lr][lc + t * 4 + 3] = v.w * 0.125f;
        }
    }
    if (tid < 64) { m_sm[tid] = -INFINITY; l_sm[tid] = 0.f; }

    float4 o4[4];
#pragma unroll
    for (int t = 0; t < 4; ++t) o4[t] = make_float4(0.f, 0.f, 0.f, 0.f);

    const int qB = (tid >> 4) << 2;    // S-compute: 4 q rows
    const int kB = (tid & 15) << 2;    // S-compute: 4 k cols
    const int qo = tid >> 2;           // O-update: owned q row
    const int dB = (tid & 3) << 4;     // O-update: 16 d cols

    for (int kt = 0; kt < NSEQ / 64; ++kt) {
        const int k0 = kt << 6;
        {   // stage K,V tiles
            const float* srcK = K + hbase + (size_t)(k0 + lr) * D_MODEL + lc;
            const float* srcV = V + hbase + (size_t)(k0 + lr) * D_MODEL + lc;
#pragma unroll
            for (int t = 0; t < 4; ++t) {
                float4 kv = ((const float4*)srcK)[t];
                float4 vv = ((const float4*)srcV)[t];
                *(float4*)&Ks[lr][lc + t * 4] = kv;
                *(float4*)&Vs[lr][lc + t * 4] = vv;
            }
        }
        __syncthreads();

        // S = (Q*scale) K^T  (4x4 per thread)
        float s[4][4] = {{0.f}};
#pragma unroll
        for (int d = 0; d < DK; d += 4) {
            float4 qv[4], kv[4];
#pragma unroll
            for (int i = 0; i < 4; ++i) qv[i] = *(const float4*)&Qs[qB + i][d];
#pragma unroll
            for (int j = 0; j < 4; ++j) kv[j] = *(const float4*)&Ks[kB + j][d];
#pragma unroll
            for (int i = 0; i < 4; ++i)
#pragma unroll
                for (int j = 0; j < 4; ++j)
                    s[i][j] += qv[i].x * kv[j].x + qv[i].y * kv[j].y +
                               qv[i].z * kv[j].z + qv[i].w * kv[j].w;
        }
#pragma unroll
        for (int i = 0; i < 4; ++i)
            *(float4*)&Ss[qB + i][kB] = make_float4(s[i][0], s[i][1], s[i][2], s[i][3]);
        __syncthreads();

        // online softmax (wave 0: one thread per q row)
        if (tid < 64) {
            const int q = tid;
            float mo = m_sm[q];
            float rm = -INFINITY;
#pragma unroll 8
            for (int k = 0; k < 64; ++k) rm = fmaxf(rm, Ss[q][k]);
            float mn = fmaxf(mo, rm);
            float al = __expf(mo - mn);   // first iter: exp(-inf)=0
            float sum = 0.f;
#pragma unroll 8
            for (int k = 0; k < 64; ++k) {
                float p = __expf(Ss[q][k] - mn);
                Ss[q][k] = p;
                sum += p;
            }
            l_sm[q] = al * l_sm[q] + sum;
            m_sm[q] = mn;
            a_sm[q] = al;
        }
        __syncthreads();

        // O = O*alpha + P @ V   (each thread: 1 q row x 16 d cols)
        {
            float al = a_sm[qo];
#pragma unroll
            for (int t = 0; t < 4; ++t) {
                o4[t].x *= al; o4[t].y *= al; o4[t].z *= al; o4[t].w *= al;
            }
            for (int k = 0; k < 64; ++k) {
                float p = Ss[qo][k];
#pragma unroll
                for (int t = 0; t < 4; ++t) {
                    float4 vv = *(const float4*)&Vs[k][dB + t * 4];
                    o4[t].x = fmaf(p, vv.x, o4[t].x);
                    o4[t].y = fmaf(p, vv.y, o4[t].y);
                    o4[t].z = fmaf(p, vv.z, o4[t].z);
                    o4[t].w = fmaf(p, vv.w, o4[t].w);
                }
            }
        }
        __syncthreads();   // protect Ks/Vs/Ss before next tile's staging
    }

    const float inv = 1.f / l_sm[qo];
    float* dst = O + hbase + (size_t)(q0 + qo) * D_MODEL + dB;
#pragma unroll
    for (int t = 0; t < 4; ++t) {
        ((float4*)dst)[t] = make_float4(o4[t].x * inv, o4[t].y * inv,
                                        o4[t].z * inv, o4[t].w * inv);
    }
}

// ---------------------------------------------------------------------------
extern "C" void kernel_launch(void* const* d_in, const int* in_sizes, int n_in,
                              void* d_out, int out_size, void* d_ws, size_t ws_size,
                              hipStream_t stream)
{
    const float* query = (const float*)d_in[0];
    const float* key_i = (const float*)d_in[1];
    const float* value = (const float*)d_in[2];
    const float* w_q   = (const float*)d_in[3];
    const float* b_q   = (const float*)d_in[4];
    const float* w_k   = (const float*)d_in[5];
    const float* b_k   = (const float*)d_in[6];
    const float* w_v   = (const float*)d_in[7];
    const float* b_v   = (const float*)d_in[8];
    const float* w_o   = (const float*)d_in[9];
    const float* b_o   = (const float*)d_in[10];
    float* out = (float*)d_out;

    const size_t elems = (size_t)MROWS * D_MODEL;   // 4M floats = 16 MB
    float* Qp = (float*)d_ws;
    float* Kp = Qp + elems;
    float* Vp = Kp + elems;
    float* Cp = Vp + elems;                          // total ws use: 64 MB

    dim3 ggrid(D_MODEL / 64, MROWS / 64);            // (16, 64)
    gemm_bt_bias<<<ggrid, 256, 0, stream>>>(query, w_q, b_q, Qp, MROWS, D_MODEL, D_MODEL);
    gemm_bt_bias<<<ggrid, 256, 0, stream>>>(key_i, w_k, b_k, Kp, MROWS, D_MODEL, D_MODEL);
    gemm_bt_bias<<<ggrid, 256, 0, stream>>>(value, w_v, b_v, Vp, MROWS, D_MODEL, D_MODEL);

    dim3 agrid(NSEQ / 64, NUM_HEADS, BATCH);         // (32, 16, 2)
    flash_attn<<<agrid, 256, 0, stream>>>(Qp, Kp, Vp, Cp);

    gemm_bt_bias<<<ggrid, 256, 0, stream>>>(Cp, w_o, b_o, out, MROWS, D_MODEL, D_MODEL);
}

// Round 2
// 862.429 us; speedup vs baseline: 2.3807x; 2.3807x over previous
//
#include <hip/hip_runtime.h>
#include <math.h>

#define D_MODEL 1024
#define NUM_HEADS 16
#define DK 64
#define BATCH 2
#define NSEQ 2048
#define MROWS (BATCH * NSEQ)   // 4096

typedef __attribute__((ext_vector_type(8))) short bf16x8;
typedef __attribute__((ext_vector_type(4))) float f32x4;

// round-to-nearest-even fp32 -> bf16 bits
static __device__ __forceinline__ unsigned short f2bf_rne(float x) {
    union { float f; unsigned u; } v; v.f = x;
    unsigned r = v.u + 0x7fffu + ((v.u >> 16) & 1u);
    return (unsigned short)(r >> 16);
}
// split x = hi + lo; hi = truncated-bf16 (exact top bits), lo = RNE bf16 of remainder.
// Dropped cross term lo*lo ~ 2^-16 relative -> fp32-level GEMM accuracy.
static __device__ __forceinline__ void split_bf16(float x, unsigned short& hi, unsigned short& lo) {
    union { float f; unsigned u; } v; v.f = x;
    unsigned hb = v.u & 0xffff0000u;
    hi = (unsigned short)(hb >> 16);
    union { unsigned u; float f; } hv; hv.u = hb;
    lo = f2bf_rne(x - hv.f);
}

// ---------------------------------------------------------------------------
// GEMM: C[M,N] = A[M,K] @ W[N,K]^T + bias[N]  (fp32 vector ALU, unchanged)
// ---------------------------------------------------------------------------
__global__ __launch_bounds__(256)
void gemm_bt_bias(const float* __restrict__ A, const float* __restrict__ W,
                  const float* __restrict__ bias, float* __restrict__ C,
                  int M, int N, int K)
{
    __shared__ float As[16][64];
    __shared__ float Ws[16][64];
    const int tid  = threadIdx.x;
    const int bm   = blockIdx.y * 64;
    const int bn   = blockIdx.x * 64;
    const int lrow = tid >> 2;
    const int lcol = (tid & 3) << 2;
    const int ty   = tid >> 4;
    const int tx   = tid & 15;

    float acc[4][4] = {{0.f}};

    for (int k0 = 0; k0 < K; k0 += 16) {
        float4 av = *(const float4*)(A + (size_t)(bm + lrow) * K + k0 + lcol);
        float4 wv = *(const float4*)(W + (size_t)(bn + lrow) * K + k0 + lcol);
        As[lcol + 0][lrow] = av.x;
        As[lcol + 1][lrow] = av.y;
        As[lcol + 2][lrow] = av.z;
        As[lcol + 3][lrow] = av.w;
        Ws[lcol + 0][lrow] = wv.x;
        Ws[lcol + 1][lrow] = wv.y;
        Ws[lcol + 2][lrow] = wv.z;
        Ws[lcol + 3][lrow] = wv.w;
        __syncthreads();
#pragma unroll
        for (int kk = 0; kk < 16; ++kk) {
            float4 a4 = *(const float4*)(&As[kk][ty << 2]);
            float4 b4 = *(const float4*)(&Ws[kk][tx << 2]);
            float a[4] = {a4.x, a4.y, a4.z, a4.w};
            float b[4] = {b4.x, b4.y, b4.z, b4.w};
#pragma unroll
            for (int i = 0; i < 4; ++i)
#pragma unroll
                for (int j = 0; j < 4; ++j)
                    acc[i][j] = fmaf(a[i], b[j], acc[i][j]);
        }
        __syncthreads();
    }

    float4 bv = *(const float4*)(bias + bn + (tx << 2));
#pragma unroll
    for (int i = 0; i < 4; ++i) {
        float4 cv;
        cv.x = acc[i][0] + bv.x;
        cv.y = acc[i][1] + bv.y;
        cv.z = acc[i][2] + bv.z;
        cv.w = acc[i][3] + bv.w;
        *(float4*)(C + (size_t)(bm + (ty << 2) + i) * N + bn + (tx << 2)) = cv;
    }
}

// ---------------------------------------------------------------------------
// Flash attention via split-bf16 MFMA (fp32-accurate).
// Block = (b, h, 64 q-rows), 4 waves; wave w owns q rows [16w, 16w+16).
// Per 64-key tile: S = Qh*Kh + Ql*Kh + Qh*Kl (MFMA), register online softmax
// with shfl_xor reductions, P split to LDS, O += Ph*Vh + Pl*Vh + Ph*Vl.
// Layouts (verified mappings): A[m=lane&15][k=quad*8+j], B[k=quad*8+j][n=lane&15],
// C/D[row=quad*4+reg][col=lane&15]. All LDS rows padded to 72 (2-way = free).
// ---------------------------------------------------------------------------
__global__ __launch_bounds__(256)
void flash_attn_mfma(const float* __restrict__ Q, const float* __restrict__ K,
                     const float* __restrict__ V, float* __restrict__ O)
{
    __shared__ __align__(16) unsigned short Qh[64][72], Ql[64][72];   // [q][d], pre-scaled by 0.125
    __shared__ __align__(16) unsigned short Kh[64][72], Kl[64][72];   // [key][d]
    __shared__ __align__(16) unsigned short Vth[64][72], Vtl[64][72]; // [d][key] (transposed)
    __shared__ __align__(16) unsigned short Psh[4][16][72], Psl[4][16][72]; // per-wave [q'][key]

    const int tid  = threadIdx.x;
    const int wv   = tid >> 6;
    const int lane = tid & 63;
    const int quad = lane >> 4;
    const int lcol = lane & 15;
    const int q0   = blockIdx.x << 6;
    const int h    = blockIdx.y;
    const int b    = blockIdx.z;
    const size_t hbase = (size_t)b * NSEQ * D_MODEL + (size_t)h * DK;

    const int lr = tid >> 2;           // 0..63 staging row
    const int lc = (tid & 3) << 4;     // 0,16,32,48 staging col group

    {   // stage Q (scaled + split) once
        const float* src = Q + hbase + (size_t)(q0 + lr) * D_MODEL + lc;
#pragma unroll
        for (int t = 0; t < 4; ++t) {
            float4 v = ((const float4*)src)[t];
            float xs[4] = {v.x, v.y, v.z, v.w};
#pragma unroll
            for (int j = 0; j < 4; ++j) {
                unsigned short hi, lo;
                split_bf16(xs[j] * 0.125f, hi, lo);
                Qh[lr][lc + t*4 + j] = hi;
                Ql[lr][lc + t*4 + j] = lo;
            }
        }
    }

    f32x4 Oacc[4];
#pragma unroll
    for (int t = 0; t < 4; ++t) Oacc[t] = (f32x4){0.f, 0.f, 0.f, 0.f};
    float mrow[4] = {-INFINITY, -INFINITY, -INFINITY, -INFINITY};
    float lrow[4] = {0.f, 0.f, 0.f, 0.f};

    for (int kt = 0; kt < NSEQ / 64; ++kt) {
        const int k0 = kt << 6;
        __syncthreads();   // previous tile's readers done (also covers Q staging on iter 0)
        {   // stage K (split) and V (split + transpose)
            const float* srcK = K + hbase + (size_t)(k0 + lr) * D_MODEL + lc;
            const float* srcV = V + hbase + (size_t)(k0 + lr) * D_MODEL + lc;
#pragma unroll
            for (int t = 0; t < 4; ++t) {
                float4 kv = ((const float4*)srcK)[t];
                float4 vv = ((const float4*)srcV)[t];
                float ks[4] = {kv.x, kv.y, kv.z, kv.w};
                float vs[4] = {vv.x, vv.y, vv.z, vv.w};
#pragma unroll
                for (int j = 0; j < 4; ++j) {
                    unsigned short hi, lo;
                    split_bf16(ks[j], hi, lo);
                    Kh[lr][lc + t*4 + j] = hi;
                    Kl[lr][lc + t*4 + j] = lo;
                    split_bf16(vs[j], hi, lo);
                    Vth[lc + t*4 + j][lr] = hi;
                    Vtl[lc + t*4 + j][lr] = lo;
                }
            }
        }
        __syncthreads();

        // Q A-fragments (rows 16*wv + lcol)
        bf16x8 aQh[2], aQl[2];
#pragma unroll
        for (int c = 0; c < 2; ++c) {
            aQh[c] = *(const bf16x8*)&Qh[(wv << 4) + lcol][c*32 + quad*8];
            aQl[c] = *(const bf16x8*)&Ql[(wv << 4) + lcol][c*32 + quad*8];
        }

        // S = Q K^T (split, 6 MFMAs per 16-key tile)
        f32x4 S[4];
#pragma unroll
        for (int t = 0; t < 4; ++t) {
            bf16x8 bKh0 = *(const bf16x8*)&Kh[(t << 4) + lcol][quad*8];
            bf16x8 bKh1 = *(const bf16x8*)&Kh[(t << 4) + lcol][32 + quad*8];
            bf16x8 bKl0 = *(const bf16x8*)&Kl[(t << 4) + lcol][quad*8];
            bf16x8 bKl1 = *(const bf16x8*)&Kl[(t << 4) + lcol][32 + quad*8];
            f32x4 acc = (f32x4){0.f, 0.f, 0.f, 0.f};
            acc = __builtin_amdgcn_mfma_f32_16x16x32_bf16(aQh[0], bKh0, acc, 0, 0, 0);
            acc = __builtin_amdgcn_mfma_f32_16x16x32_bf16(aQh[1], bKh1, acc, 0, 0, 0);
            acc = __builtin_amdgcn_mfma_f32_16x16x32_bf16(aQl[0], bKh0, acc, 0, 0, 0);
            acc = __builtin_amdgcn_mfma_f32_16x16x32_bf16(aQl[1], bKh1, acc, 0, 0, 0);
            acc = __builtin_amdgcn_mfma_f32_16x16x32_bf16(aQh[0], bKl0, acc, 0, 0, 0);
            acc = __builtin_amdgcn_mfma_f32_16x16x32_bf16(aQh[1], bKl1, acc, 0, 0, 0);
            S[t] = acc;
        }

        // row max over 64 keys: in-register over t, then across the 16 lanes of the quad
        float rmax[4];
#pragma unroll
        for (int r = 0; r < 4; ++r)
            rmax[r] = fmaxf(fmaxf(S[0][r], S[1][r]), fmaxf(S[2][r], S[3][r]));
#pragma unroll
        for (int off = 1; off < 16; off <<= 1)
#pragma unroll
            for (int r = 0; r < 4; ++r)
                rmax[r] = fmaxf(rmax[r], __shfl_xor(rmax[r], off, 64));

        float alpha[4];
#pragma unroll
        for (int r = 0; r < 4; ++r) {
            float mn = fmaxf(mrow[r], rmax[r]);
            alpha[r] = __expf(mrow[r] - mn);   // first iter: exp(-inf)=0
            mrow[r] = mn;
        }

        float p[4][4], psum[4] = {0.f, 0.f, 0.f, 0.f};
#pragma unroll
        for (int t = 0; t < 4; ++t)
#pragma unroll
            for (int r = 0; r < 4; ++r) {
                float pv = __expf(S[t][r] - mrow[r]);
                p[t][r] = pv;
                psum[r] += pv;
            }
#pragma unroll
        for (int off = 1; off < 16; off <<= 1)
#pragma unroll
            for (int r = 0; r < 4; ++r)
                psum[r] += __shfl_xor(psum[r], off, 64);
#pragma unroll
        for (int r = 0; r < 4; ++r)
            lrow[r] = alpha[r] * lrow[r] + psum[r];

        // write P (split) to this wave's LDS region: C-layout -> [q'][key]
#pragma unroll
        for (int t = 0; t < 4; ++t)
#pragma unroll
            for (int r = 0; r < 4; ++r) {
                unsigned short hi, lo;
                split_bf16(p[t][r], hi, lo);
                Psh[wv][quad*4 + r][(t << 4) + lcol] = hi;
                Psl[wv][quad*4 + r][(t << 4) + lcol] = lo;
            }
        __syncthreads();

        // P A-fragments
        bf16x8 aPh[2], aPl[2];
#pragma unroll
        for (int c = 0; c < 2; ++c) {
            aPh[c] = *(const bf16x8*)&Psh[wv][lcol][c*32 + quad*8];
            aPl[c] = *(const bf16x8*)&Psl[wv][lcol][c*32 + quad*8];
        }

        // O = O*alpha + P V (split, 6 MFMAs per 16-dim tile)
#pragma unroll
        for (int t = 0; t < 4; ++t) {
            f32x4 o = Oacc[t];
#pragma unroll
            for (int r = 0; r < 4; ++r) o[r] *= alpha[r];
            bf16x8 bVh0 = *(const bf16x8*)&Vth[(t << 4) + lcol][quad*8];
            bf16x8 bVh1 = *(const bf16x8*)&Vth[(t << 4) + lcol][32 + quad*8];
            bf16x8 bVl0 = *(const bf16x8*)&Vtl[(t << 4) + lcol][quad*8];
            bf16x8 bVl1 = *(const bf16x8*)&Vtl[(t << 4) + lcol][32 + quad*8];
            o = __builtin_amdgcn_mfma_f32_16x16x32_bf16(aPh[0], bVh0, o, 0, 0, 0);
            o = __builtin_amdgcn_mfma_f32_16x16x32_bf16(aPh[1], bVh1, o, 0, 0, 0);
            o = __builtin_amdgcn_mfma_f32_16x16x32_bf16(aPl[0], bVh0, o, 0, 0, 0);
            o = __builtin_amdgcn_mfma_f32_16x16x32_bf16(aPl[1], bVh1, o, 0, 0, 0);
            o = __builtin_amdgcn_mfma_f32_16x16x32_bf16(aPh[0], bVl0, o, 0, 0, 0);
            o = __builtin_amdgcn_mfma_f32_16x16x32_bf16(aPh[1], bVl1, o, 0, 0, 0);
            Oacc[t] = o;
        }
    }

    // epilogue: normalize and store (C-layout scatter, 64B-coalesced per (t,r))
    float inv[4];
#pragma unroll
    for (int r = 0; r < 4; ++r) inv[r] = 1.f / lrow[r];
    float* dst = O + hbase + (size_t)(q0 + (wv << 4)) * D_MODEL;
#pragma unroll
    for (int t = 0; t < 4; ++t)
#pragma unroll
        for (int r = 0; r < 4; ++r)
            dst[(size_t)(quad*4 + r) * D_MODEL + (t << 4) + lcol] = Oacc[t][r] * inv[r];
}

// ---------------------------------------------------------------------------
extern "C" void kernel_launch(void* const* d_in, const int* in_sizes, int n_in,
                              void* d_out, int out_size, void* d_ws, size_t ws_size,
                              hipStream_t stream)
{
    const float* query = (const float*)d_in[0];
    const float* key_i = (const float*)d_in[1];
    const float* value = (const float*)d_in[2];
    const float* w_q   = (const float*)d_in[3];
    const float* b_q   = (const float*)d_in[4];
    const float* w_k   = (const float*)d_in[5];
    const float* b_k   = (const float*)d_in[6];
    const float* w_v   = (const float*)d_in[7];
    const float* b_v   = (const float*)d_in[8];
    const float* w_o   = (const float*)d_in[9];
    const float* b_o   = (const float*)d_in[10];
    float* out = (float*)d_out;

    const size_t elems = (size_t)MROWS * D_MODEL;   // 4M floats = 16 MB
    float* Qp = (float*)d_ws;
    float* Kp = Qp + elems;
    float* Vp = Kp + elems;
    float* Cp = Vp + elems;                          // total ws use: 64 MB

    dim3 ggrid(D_MODEL / 64, MROWS / 64);            // (16, 64)
    gemm_bt_bias<<<ggrid, 256, 0, stream>>>(query, w_q, b_q, Qp, MROWS, D_MODEL, D_MODEL);
    gemm_bt_bias<<<ggrid, 256, 0, stream>>>(key_i, w_k, b_k, Kp, MROWS, D_MODEL, D_MODEL);
    gemm_bt_bias<<<ggrid, 256, 0, stream>>>(value, w_v, b_v, Vp, MROWS, D_MODEL, D_MODEL);

    dim3 agrid(NSEQ / 64, NUM_HEADS, BATCH);         // (32, 16, 2)
    flash_attn_mfma<<<agrid, 256, 0, stream>>>(Qp, Kp, Vp, Cp);

    gemm_bt_bias<<<ggrid, 256, 0, stream>>>(Cp, w_o, b_o, out, MROWS, D_MODEL, D_MODEL);
}

// Round 3
// 507.992 us; speedup vs baseline: 4.0418x; 1.6977x over previous
//
#include <hip/hip_runtime.h>
#include <math.h>

#define D_MODEL 1024
#define NUM_HEADS 16
#define DK 64
#define BATCH 2
#define NSEQ 2048
#define MROWS (BATCH * NSEQ)   // 4096

typedef __attribute__((ext_vector_type(8))) short bf16x8;
typedef __attribute__((ext_vector_type(4))) float f32x4;
typedef unsigned short u16;

// round-to-nearest-even fp32 -> bf16 bits
static __device__ __forceinline__ u16 f2bf_rne(float x) {
    union { float f; unsigned u; } v; v.f = x;
    unsigned r = v.u + 0x7fffu + ((v.u >> 16) & 1u);
    return (u16)(r >> 16);
}
// split x = hi + lo; hi = truncated-bf16, lo = RNE bf16 of remainder.
static __device__ __forceinline__ void split_bf16(float x, u16& hi, u16& lo) {
    union { float f; unsigned u; } v; v.f = x;
    unsigned hb = v.u & 0xffff0000u;
    hi = (u16)(hb >> 16);
    union { unsigned u; float f; } hv; hv.u = hb;
    lo = f2bf_rne(x - hv.f);
}

#define AS1 __attribute__((address_space(1)))
#define AS3 __attribute__((address_space(3)))
static __device__ __forceinline__ void gl_lds16(const void* g, void* l) {
    // async 16B/lane global->LDS; LDS dest = wave-uniform base + lane*16
    __builtin_amdgcn_global_load_lds((AS1 void*)(uintptr_t)g, (AS3 void*)l, 16, 0, 0);
}

// ---------------------------------------------------------------------------
// fp32 -> split bf16 planes (hi, lo). n8 = elems/8.
// ---------------------------------------------------------------------------
__global__ __launch_bounds__(256)
void split_f32(const float* __restrict__ src, u16* __restrict__ h,
               u16* __restrict__ l, int n8)
{
    const int i = blockIdx.x * 256 + threadIdx.x;
    if (i >= n8) return;
    float4 a = ((const float4*)src)[2 * i];
    float4 b = ((const float4*)src)[2 * i + 1];
    float x[8] = {a.x, a.y, a.z, a.w, b.x, b.y, b.z, b.w};
    u16 hh[8], ll[8];
#pragma unroll
    for (int j = 0; j < 8; ++j) split_bf16(x[j], hh[j], ll[j]);
    *(uint4*)(h + 8 * (size_t)i) = *(uint4*)hh;
    *(uint4*)(l + 8 * (size_t)i) = *(uint4*)ll;
}

// ---------------------------------------------------------------------------
// MFMA GEMM, split-bf16 (3-term): C = A @ W^T + bias, optional scale.
// A planes [M][K], W planes [N][K]. BM=128, BN=64, BK=32, 256 thr (4 waves,
// 2x2), wave tile 64x32 (4x2 16x16 acc). global_load_lds width-16 staging.
// Output: fp32 (outF) or split planes (outH/outL).
// ---------------------------------------------------------------------------
#define BM 128
#define BN 64
#define BK 32

__global__ __launch_bounds__(256)
void gemm_mfma_split(const u16* __restrict__ Ah, const u16* __restrict__ Al,
                     const u16* __restrict__ Wh, const u16* __restrict__ Wl,
                     const float* __restrict__ bias,
                     float* __restrict__ outF,
                     u16* __restrict__ outH, u16* __restrict__ outL,
                     float scale, int M, int N, int K)
{
    __shared__ u16 As_h[BM][BK], As_l[BM][BK];   // 8 KB each
    __shared__ u16 Ws_h[BN][BK], Ws_l[BN][BK];   // 4 KB each

    const int tid  = threadIdx.x;
    const int wv   = tid >> 6, lane = tid & 63;
    const int quad = lane >> 4, lcol = lane & 15;
    const int bm = blockIdx.y * BM, bn = blockIdx.x * BN;
    const int wm = (wv >> 1) * 64, wn = (wv & 1) * 32;
    const int srow = lane >> 2;          // staging row within 16-row group
    const int scol = (lane & 3) * 8;     // staging col (elements)

    f32x4 acc[4][2];
#pragma unroll
    for (int i = 0; i < 4; ++i)
#pragma unroll
        for (int j = 0; j < 2; ++j) acc[i][j] = (f32x4){0.f, 0.f, 0.f, 0.f};

    for (int k0 = 0; k0 < K; k0 += BK) {
        __syncthreads();
#pragma unroll
        for (int r = 0; r < 2; ++r) {
            const int row0 = wv * 32 + r * 16;
            gl_lds16(Ah + (size_t)(bm + row0 + srow) * K + k0 + scol, &As_h[row0][0]);
            gl_lds16(Al + (size_t)(bm + row0 + srow) * K + k0 + scol, &As_l[row0][0]);
        }
        {
            const int row0 = wv * 16;
            gl_lds16(Wh + (size_t)(bn + row0 + srow) * K + k0 + scol, &Ws_h[row0][0]);
            gl_lds16(Wl + (size_t)(bn + row0 + srow) * K + k0 + scol, &Ws_l[row0][0]);
        }
        __syncthreads();

        bf16x8 bh[2], bl[2];
#pragma unroll
        for (int j = 0; j < 2; ++j) {
            bh[j] = *(const bf16x8*)&Ws_h[wn + j * 16 + lcol][quad * 8];
            bl[j] = *(const bf16x8*)&Ws_l[wn + j * 16 + lcol][quad * 8];
        }
#pragma unroll
        for (int i = 0; i < 4; ++i) {
            bf16x8 ah = *(const bf16x8*)&As_h[wm + i * 16 + lcol][quad * 8];
            bf16x8 al = *(const bf16x8*)&As_l[wm + i * 16 + lcol][quad * 8];
#pragma unroll
            for (int j = 0; j < 2; ++j) {
                acc[i][j] = __builtin_amdgcn_mfma_f32_16x16x32_bf16(ah, bh[j], acc[i][j], 0, 0, 0);
                acc[i][j] = __builtin_amdgcn_mfma_f32_16x16x32_bf16(al, bh[j], acc[i][j], 0, 0, 0);
                acc[i][j] = __builtin_amdgcn_mfma_f32_16x16x32_bf16(ah, bl[j], acc[i][j], 0, 0, 0);
            }
        }
    }

    // epilogue: C/D layout row=quad*4+r, col=lcol
#pragma unroll
    for (int j = 0; j < 2; ++j) {
        const int col = bn + wn + j * 16 + lcol;
        const float bj = bias[col];
#pragma unroll
        for (int i = 0; i < 4; ++i) {
#pragma unroll
            for (int r = 0; r < 4; ++r) {
                const int row = bm + wm + i * 16 + quad * 4 + r;
                const float v = (acc[i][j][r] + bj) * scale;
                const size_t o = (size_t)row * N + col;
                if (outF) {
                    outF[o] = v;
                } else {
                    u16 hi, lo;
                    split_bf16(v, hi, lo);
                    outH[o] = hi;
                    outL[o] = lo;
                }
            }
        }
    }
}

// ---------------------------------------------------------------------------
// Per-head transpose of V planes: out[b][h][d][n] = in[b][n][h*64+d]
// ---------------------------------------------------------------------------
__global__ __launch_bounds__(256)
void transpose_heads(const u16* __restrict__ inh, const u16* __restrict__ inl,
                     u16* __restrict__ outh, u16* __restrict__ outl)
{
    __shared__ u16 T[64][72];
    const int tid = threadIdx.x;
    const int n0 = blockIdx.x * 64;
    const int h = blockIdx.y, b = blockIdx.z;
    const int lr = tid >> 2, lc = (tid & 3) * 16;
    const size_t ibase = (size_t)(b * NSEQ) * D_MODEL + h * DK;
    const size_t obase = (size_t)(b * NUM_HEADS + h) * DK * NSEQ;
    const u16* src[2] = {inh, inl};
    u16* dst[2] = {outh, outl};
#pragma unroll
    for (int p = 0; p < 2; ++p) {
        __syncthreads();
        const u16* s = src[p] + ibase + (size_t)(n0 + lr) * D_MODEL + lc;
        *(uint4*)&T[lr][lc]     = *(const uint4*)s;
        *(uint4*)&T[lr][lc + 8] = *(const uint4*)(s + 8);
        __syncthreads();
        u16 vals[16];
#pragma unroll
        for (int j = 0; j < 16; ++j) vals[j] = T[lc + j][lr];
        u16* d = dst[p] + obase + (size_t)lr * NSEQ + n0 + lc;
        *(uint4*)d       = *(uint4*)&vals[0];
        *(uint4*)(d + 8) = *(uint4*)&vals[8];
    }
}

// ---------------------------------------------------------------------------
// Flash attention, split-bf16 MFMA, all operands pre-split bf16 planes.
// Q planes pre-scaled by 0.125. V pre-transposed per head [b][h][d][n].
// Output ctx as split planes (heads interleaved, [b][n][h*64+d]).
// ---------------------------------------------------------------------------
__global__ __launch_bounds__(256)
void flash_attn_mfma(const u16* __restrict__ Qh_g, const u16* __restrict__ Ql_g,
                     const u16* __restrict__ Kh_g, const u16* __restrict__ Kl_g,
                     const u16* __restrict__ Vth_g, const u16* __restrict__ Vtl_g,
                     u16* __restrict__ Ch_g, u16* __restrict__ Cl_g)
{
    __shared__ __align__(16) u16 Qs_h[64][72], Qs_l[64][72];
    __shared__ __align__(16) u16 Ks_h[64][72], Ks_l[64][72];
    __shared__ __align__(16) u16 Vs_h[64][72], Vs_l[64][72];   // [d][key]
    __shared__ __align__(16) u16 Ps_h[4][16][72], Ps_l[4][16][72];

    const int tid  = threadIdx.x;
    const int wv   = tid >> 6;
    const int lane = tid & 63;
    const int quad = lane >> 4;
    const int lcol = lane & 15;
    const int q0   = blockIdx.x << 6;
    const int h    = blockIdx.y;
    const int b    = blockIdx.z;
    const size_t hbase  = (size_t)b * NSEQ * D_MODEL + (size_t)h * DK;
    const size_t vtbase = (size_t)(b * NUM_HEADS + h) * DK * NSEQ;

    const int lr = tid >> 2;           // staging row 0..63
    const int lc = (tid & 3) << 4;     // staging col group (16 shorts)

    {   // stage Q once (pure copy; scale folded into projection)
        const u16* sh = Qh_g + hbase + (size_t)(q0 + lr) * D_MODEL + lc;
        const u16* sl = Ql_g + hbase + (size_t)(q0 + lr) * D_MODEL + lc;
        *(uint4*)&Qs_h[lr][lc]     = *(const uint4*)sh;
        *(uint4*)&Qs_h[lr][lc + 8] = *(const uint4*)(sh + 8);
        *(uint4*)&Qs_l[lr][lc]     = *(const uint4*)sl;
        *(uint4*)&Qs_l[lr][lc + 8] = *(const uint4*)(sl + 8);
    }
    __syncthreads();

    // Q A-fragments (rows 16*wv + lcol) — static across tiles, hoisted
    bf16x8 aQh[2], aQl[2];
#pragma unroll
    for (int c = 0; c < 2; ++c) {
        aQh[c] = *(const bf16x8*)&Qs_h[(wv << 4) + lcol][c * 32 + quad * 8];
        aQl[c] = *(const bf16x8*)&Qs_l[(wv << 4) + lcol][c * 32 + quad * 8];
    }

    f32x4 Oacc[4];
#pragma unroll
    for (int t = 0; t < 4; ++t) Oacc[t] = (f32x4){0.f, 0.f, 0.f, 0.f};
    float mrow[4] = {-INFINITY, -INFINITY, -INFINITY, -INFINITY};
    float lrow[4] = {0.f, 0.f, 0.f, 0.f};

    for (int kt = 0; kt < NSEQ / 64; ++kt) {
        const int k0 = kt << 6;
        __syncthreads();   // previous tile's readers done
        {   // stage K rows [key][d] and Vt rows [d][key] — pure copies
            const u16* skh = Kh_g + hbase + (size_t)(k0 + lr) * D_MODEL + lc;
            const u16* skl = Kl_g + hbase + (size_t)(k0 + lr) * D_MODEL + lc;
            const u16* svh = Vth_g + vtbase + (size_t)lr * NSEQ + k0 + lc;
            const u16* svl = Vtl_g + vtbase + (size_t)lr * NSEQ + k0 + lc;
            *(uint4*)&Ks_h[lr][lc]     = *(const uint4*)skh;
            *(uint4*)&Ks_h[lr][lc + 8] = *(const uint4*)(skh + 8);
            *(uint4*)&Ks_l[lr][lc]     = *(const uint4*)skl;
            *(uint4*)&Ks_l[lr][lc + 8] = *(const uint4*)(skl + 8);
            *(uint4*)&Vs_h[lr][lc]     = *(const uint4*)svh;
            *(uint4*)&Vs_h[lr][lc + 8] = *(const uint4*)(svh + 8);
            *(uint4*)&Vs_l[lr][lc]     = *(const uint4*)svl;
            *(uint4*)&Vs_l[lr][lc + 8] = *(const uint4*)(svl + 8);
        }
        __syncthreads();

        // S = Q K^T (split, 6 MFMAs per 16-key tile)
        f32x4 S[4];
#pragma unroll
        for (int t = 0; t < 4; ++t) {
            bf16x8 bKh0 = *(const bf16x8*)&Ks_h[(t << 4) + lcol][quad * 8];
            bf16x8 bKh1 = *(const bf16x8*)&Ks_h[(t << 4) + lcol][32 + quad * 8];
            bf16x8 bKl0 = *(const bf16x8*)&Ks_l[(t << 4) + lcol][quad * 8];
            bf16x8 bKl1 = *(const bf16x8*)&Ks_l[(t << 4) + lcol][32 + quad * 8];
            f32x4 acc = (f32x4){0.f, 0.f, 0.f, 0.f};
            acc = __builtin_amdgcn_mfma_f32_16x16x32_bf16(aQh[0], bKh0, acc, 0, 0, 0);
            acc = __builtin_amdgcn_mfma_f32_16x16x32_bf16(aQh[1], bKh1, acc, 0, 0, 0);
            acc = __builtin_amdgcn_mfma_f32_16x16x32_bf16(aQl[0], bKh0, acc, 0, 0, 0);
            acc = __builtin_amdgcn_mfma_f32_16x16x32_bf16(aQl[1], bKh1, acc, 0, 0, 0);
            acc = __builtin_amdgcn_mfma_f32_16x16x32_bf16(aQh[0], bKl0, acc, 0, 0, 0);
            acc = __builtin_amdgcn_mfma_f32_16x16x32_bf16(aQh[1], bKl1, acc, 0, 0, 0);
            S[t] = acc;
        }

        // online softmax (in-register, shfl reduction over 16 lanes)
        float rmax[4];
#pragma unroll
        for (int r = 0; r < 4; ++r)
            rmax[r] = fmaxf(fmaxf(S[0][r], S[1][r]), fmaxf(S[2][r], S[3][r]));
#pragma unroll
        for (int off = 1; off < 16; off <<= 1)
#pragma unroll
            for (int r = 0; r < 4; ++r)
                rmax[r] = fmaxf(rmax[r], __shfl_xor(rmax[r], off, 64));

        float alpha[4];
#pragma unroll
        for (int r = 0; r < 4; ++r) {
            float mn = fmaxf(mrow[r], rmax[r]);
            alpha[r] = __expf(mrow[r] - mn);
            mrow[r] = mn;
        }

        float p[4][4], psum[4] = {0.f, 0.f, 0.f, 0.f};
#pragma unroll
        for (int t = 0; t < 4; ++t)
#pragma unroll
            for (int r = 0; r < 4; ++r) {
                float pv = __expf(S[t][r] - mrow[r]);
                p[t][r] = pv;
                psum[r] += pv;
            }
#pragma unroll
        for (int off = 1; off < 16; off <<= 1)
#pragma unroll
            for (int r = 0; r < 4; ++r)
                psum[r] += __shfl_xor(psum[r], off, 64);
#pragma unroll
        for (int r = 0; r < 4; ++r)
            lrow[r] = alpha[r] * lrow[r] + psum[r];

        // write P (split) to wave's LDS region: C-layout -> [q'][key]
#pragma unroll
        for (int t = 0; t < 4; ++t)
#pragma unroll
            for (int r = 0; r < 4; ++r) {
                u16 hi, lo;
                split_bf16(p[t][r], hi, lo);
                Ps_h[wv][quad * 4 + r][(t << 4) + lcol] = hi;
                Ps_l[wv][quad * 4 + r][(t << 4) + lcol] = lo;
            }
        __syncthreads();

        bf16x8 aPh[2], aPl[2];
#pragma unroll
        for (int c = 0; c < 2; ++c) {
            aPh[c] = *(const bf16x8*)&Ps_h[wv][lcol][c * 32 + quad * 8];
            aPl[c] = *(const bf16x8*)&Ps_l[wv][lcol][c * 32 + quad * 8];
        }

        // O = O*alpha + P V (split, 6 MFMAs per 16-dim tile)
#pragma unroll
        for (int t = 0; t < 4; ++t) {
            f32x4 o = Oacc[t];
#pragma unroll
            for (int r = 0; r < 4; ++r) o[r] *= alpha[r];
            bf16x8 bVh0 = *(const bf16x8*)&Vs_h[(t << 4) + lcol][quad * 8];
            bf16x8 bVh1 = *(const bf16x8*)&Vs_h[(t << 4) + lcol][32 + quad * 8];
            bf16x8 bVl0 = *(const bf16x8*)&Vs_l[(t << 4) + lcol][quad * 8];
            bf16x8 bVl1 = *(const bf16x8*)&Vs_l[(t << 4) + lcol][32 + quad * 8];
            o = __builtin_amdgcn_mfma_f32_16x16x32_bf16(aPh[0], bVh0, o, 0, 0, 0);
            o = __builtin_amdgcn_mfma_f32_16x16x32_bf16(aPh[1], bVh1, o, 0, 0, 0);
            o = __builtin_amdgcn_mfma_f32_16x16x32_bf16(aPl[0], bVh0, o, 0, 0, 0);
            o = __builtin_amdgcn_mfma_f32_16x16x32_bf16(aPl[1], bVh1, o, 0, 0, 0);
            o = __builtin_amdgcn_mfma_f32_16x16x32_bf16(aPh[0], bVl0, o, 0, 0, 0);
            o = __builtin_amdgcn_mfma_f32_16x16x32_bf16(aPh[1], bVl1, o, 0, 0, 0);
            Oacc[t] = o;
        }
    }

    // epilogue: normalize, split, store ctx planes
    float inv[4];
#pragma unroll
    for (int r = 0; r < 4; ++r) inv[r] = 1.f / lrow[r];
    const size_t rowbase = hbase + (size_t)(q0 + (wv << 4)) * D_MODEL;
#pragma unroll
    for (int t = 0; t < 4; ++t)
#pragma unroll
        for (int r = 0; r < 4; ++r) {
            u16 hi, lo;
            split_bf16(Oacc[t][r] * inv[r], hi, lo);
            const size_t o = rowbase + (size_t)(quad * 4 + r) * D_MODEL + (t << 4) + lcol;
            Ch_g[o] = hi;
            Cl_g[o] = lo;
        }
}

// ---------------------------------------------------------------------------
extern "C" void kernel_launch(void* const* d_in, const int* in_sizes, int n_in,
                              void* d_out, int out_size, void* d_ws, size_t ws_size,
                              hipStream_t stream)
{
    const float* query = (const float*)d_in[0];
    const float* key_i = (const float*)d_in[1];
    const float* value = (const float*)d_in[2];
    const float* w_q   = (const float*)d_in[3];
    const float* b_q   = (const float*)d_in[4];
    const float* w_k   = (const float*)d_in[5];
    const float* b_k   = (const float*)d_in[6];
    const float* w_v   = (const float*)d_in[7];
    const float* b_v   = (const float*)d_in[8];
    const float* w_o   = (const float*)d_in[9];
    const float* b_o   = (const float*)d_in[10];
    float* out = (float*)d_out;

    const size_t WE = (size_t)D_MODEL * D_MODEL;   // 1M elems per weight
    const size_t AE = (size_t)MROWS * D_MODEL;     // 4M elems per activation

    u16* p = (u16*)d_ws;
    // weight planes: 8 x 1M u16 = 16 MB
    u16* Wqh = p;            u16* Wql = Wqh + WE;
    u16* Wkh = Wql + WE;     u16* Wkl = Wkh + WE;
    u16* Wvh = Wkl + WE;     u16* Wvl = Wvh + WE;
    u16* Woh = Wvl + WE;     u16* Wol = Woh + WE;
    // input split buffer (reused for query/key/value), later Vt planes: 16 MB
    u16* INh = Wol + WE;     u16* INl = INh + AE;
    u16* VTh = INh;          u16* VTl = INl;        // alias (inbuf dead by then)
    // projection planes: 48 MB
    u16* Qh = INl + AE;      u16* Ql = Qh + AE;
    u16* Kh = Ql + AE;       u16* Kl = Kh + AE;
    u16* Vh = Kl + AE;       u16* Vl = Vh + AE;
    // ctx planes alias V planes (V dead after transpose)
    u16* Ch = Vh;            u16* Cl = Vl;
    // total: 80 MB

    const int wgrid = (int)(WE / 8 / 256);   // 512
    const int agrid = (int)(AE / 8 / 256);   // 2048

    split_f32<<<wgrid, 256, 0, stream>>>(w_q, Wqh, Wql, (int)(WE / 8));
    split_f32<<<wgrid, 256, 0, stream>>>(w_k, Wkh, Wkl, (int)(WE / 8));
    split_f32<<<wgrid, 256, 0, stream>>>(w_v, Wvh, Wvl, (int)(WE / 8));
    split_f32<<<wgrid, 256, 0, stream>>>(w_o, Woh, Wol, (int)(WE / 8));

    dim3 ggrid(D_MODEL / BN, MROWS / BM);   // (16, 32)

    split_f32<<<agrid, 256, 0, stream>>>(query, INh, INl, (int)(AE / 8));
    gemm_mfma_split<<<ggrid, 256, 0, stream>>>(INh, INl, Wqh, Wql, b_q,
                                               nullptr, Qh, Ql, 0.125f,
                                               MROWS, D_MODEL, D_MODEL);
    split_f32<<<agrid, 256, 0, stream>>>(key_i, INh, INl, (int)(AE / 8));
    gemm_mfma_split<<<ggrid, 256, 0, stream>>>(INh, INl, Wkh, Wkl, b_k,
                                               nullptr, Kh, Kl, 1.0f,
                                               MROWS, D_MODEL, D_MODEL);
    split_f32<<<agrid, 256, 0, stream>>>(value, INh, INl, (int)(AE / 8));
    gemm_mfma_split<<<ggrid, 256, 0, stream>>>(INh, INl, Wvh, Wvl, b_v,
                                               nullptr, Vh, Vl, 1.0f,
                                               MROWS, D_MODEL, D_MODEL);

    dim3 tgrid(NSEQ / 64, NUM_HEADS, BATCH);
    transpose_heads<<<tgrid, 256, 0, stream>>>(Vh, Vl, VTh, VTl);

    dim3 fgrid(NSEQ / 64, NUM_HEADS, BATCH);
    flash_attn_mfma<<<fgrid, 256, 0, stream>>>(Qh, Ql, Kh, Kl, VTh, VTl, Ch, Cl);

    gemm_mfma_split<<<ggrid, 256, 0, stream>>>(Ch, Cl, Woh, Wol, b_o,
                                               out, nullptr, nullptr, 1.0f,
                                               MROWS, D_MODEL, D_MODEL);
}

// Round 4
// 446.326 us; speedup vs baseline: 4.6003x; 1.1382x over previous
//
#include <hip/hip_runtime.h>
#include <math.h>

#define D_MODEL 1024
#define NUM_HEADS 16
#define DK 64
#define BATCH 2
#define NSEQ 2048
#define MROWS (BATCH * NSEQ)   // 4096

typedef __attribute__((ext_vector_type(8))) short bf16x8;
typedef __attribute__((ext_vector_type(4))) float f32x4;
typedef unsigned short u16;

// round-to-nearest-even fp32 -> bf16 bits
static __device__ __forceinline__ u16 f2bf_rne(float x) {
    union { float f; unsigned u; } v; v.f = x;
    unsigned r = v.u + 0x7fffu + ((v.u >> 16) & 1u);
    return (u16)(r >> 16);
}
// split x = hi + lo; hi = truncated-bf16, lo = RNE bf16 of remainder.
static __device__ __forceinline__ void split_bf16(float x, u16& hi, u16& lo) {
    union { float f; unsigned u; } v; v.f = x;
    unsigned hb = v.u & 0xffff0000u;
    hi = (u16)(hb >> 16);
    union { unsigned u; float f; } hv; hv.u = hb;
    lo = f2bf_rne(x - hv.f);
}

#define AS1 __attribute__((address_space(1)))
#define AS3 __attribute__((address_space(3)))
static __device__ __forceinline__ void gl_lds16(const void* g, void* l) {
    __builtin_amdgcn_global_load_lds((AS1 void*)(uintptr_t)g, (AS3 void*)l, 16, 0, 0);
}

// ---------------------------------------------------------------------------
// fp32 -> split bf16 planes. n8 = elems/8.
// ---------------------------------------------------------------------------
__global__ __launch_bounds__(256)
void split_f32(const float* __restrict__ src, u16* __restrict__ h,
               u16* __restrict__ l, int n8)
{
    const int i = blockIdx.x * 256 + threadIdx.x;
    if (i >= n8) return;
    float4 a = ((const float4*)src)[2 * i];
    float4 b = ((const float4*)src)[2 * i + 1];
    float x[8] = {a.x, a.y, a.z, a.w, b.x, b.y, b.z, b.w};
    u16 hh[8], ll[8];
#pragma unroll
    for (int j = 0; j < 8; ++j) split_bf16(x[j], hh[j], ll[j]);
    *(uint4*)(h + 8 * (size_t)i) = *(uint4*)hh;
    *(uint4*)(l + 8 * (size_t)i) = *(uint4*)ll;
}

// Fused 4-way weight split: blockIdx.y selects the weight matrix.
struct SplitArgs { const float* src[4]; u16* h[4]; u16* l[4]; };
__global__ __launch_bounds__(256)
void split_f32_multi(SplitArgs args, int n8)
{
    const int w = blockIdx.y;
    const int i = blockIdx.x * 256 + threadIdx.x;
    if (i >= n8) return;
    const float* src = args.src[w];
    float4 a = ((const float4*)src)[2 * i];
    float4 b = ((const float4*)src)[2 * i + 1];
    float x[8] = {a.x, a.y, a.z, a.w, b.x, b.y, b.z, b.w};
    u16 hh[8], ll[8];
#pragma unroll
    for (int j = 0; j < 8; ++j) split_bf16(x[j], hh[j], ll[j]);
    *(uint4*)(args.h[w] + 8 * (size_t)i) = *(uint4*)hh;
    *(uint4*)(args.l[w] + 8 * (size_t)i) = *(uint4*)ll;
}

// ---------------------------------------------------------------------------
// MFMA GEMM, split-bf16 (3-term): C = (A @ W^T + bias) * scale.
// BM=128, BN=64, BK=64, 256 thr (4 waves 2x2), wave tile 64x32.
// LDS rows are 128B (64 u16) with 16B-granule XOR swizzle (slot = g ^ (row&7))
// applied on the GLOBAL side of global_load_lds -> conflict-free ds_read_b128.
// ---------------------------------------------------------------------------
#define GBM 128
#define GBN 64
#define GBK 64

__global__ __launch_bounds__(256)
void gemm_mfma_split(const u16* __restrict__ Ah, const u16* __restrict__ Al,
                     const u16* __restrict__ Wh, const u16* __restrict__ Wl,
                     const float* __restrict__ bias,
                     float* __restrict__ outF,
                     u16* __restrict__ outH, u16* __restrict__ outL,
                     float scale, int M, int N, int K)
{
    __shared__ u16 As_h[GBM][GBK], As_l[GBM][GBK];   // 16 KB each
    __shared__ u16 Ws_h[GBN][GBK], Ws_l[GBN][GBK];   // 8 KB each

    const int tid  = threadIdx.x;
    const int wv   = tid >> 6, lane = tid & 63;
    const int quad = lane >> 4, lcol = lane & 15;
    const int bm = blockIdx.y * GBM, bn = blockIdx.x * GBN;
    const int wm = (wv >> 1) * 64, wn = (wv & 1) * 32;
    // staging: lane = (sj,sg): row offset sj in 8-row group, granule sg;
    // fetch global granule sg^sj so LDS slot p of row r holds global granule p^(r&7)
    const int sj = lane >> 3, sg = lane & 7;
    const int sgx8 = ((sg ^ sj) << 3);      // u16 column offset

    f32x4 acc[4][2];
#pragma unroll
    for (int i = 0; i < 4; ++i)
#pragma unroll
        for (int j = 0; j < 2; ++j) acc[i][j] = (f32x4){0.f, 0.f, 0.f, 0.f};

    for (int k0 = 0; k0 < K; k0 += GBK) {
        __syncthreads();
        // A: wave stages rows [wv*32, wv*32+32), both planes (4 instrs x 8 rows each)
#pragma unroll
        for (int c = 0; c < 4; ++c) {
            const int r0 = wv * 32 + c * 8;
            gl_lds16(Ah + (size_t)(bm + r0 + sj) * K + k0 + sgx8, &As_h[r0][0]);
            gl_lds16(Al + (size_t)(bm + r0 + sj) * K + k0 + sgx8, &As_l[r0][0]);
        }
        // W: wave stages rows [wv*16, wv*16+16), both planes
#pragma unroll
        for (int c = 0; c < 2; ++c) {
            const int r0 = wv * 16 + c * 8;
            gl_lds16(Wh + (size_t)(bn + r0 + sj) * K + k0 + sgx8, &Ws_h[r0][0]);
            gl_lds16(Wl + (size_t)(bn + r0 + sj) * K + k0 + sgx8, &Ws_l[r0][0]);
        }
        __syncthreads();

#pragma unroll
        for (int hf = 0; hf < 2; ++hf) {
            const int sl = ((((hf << 2) + quad) ^ (lcol & 7)) << 3);  // swizzled u16 offset
            bf16x8 bh[2], bl[2];
#pragma unroll
            for (int j = 0; j < 2; ++j) {
                const int rn = wn + (j << 4) + lcol;
                bh[j] = *(const bf16x8*)&Ws_h[rn][sl];
                bl[j] = *(const bf16x8*)&Ws_l[rn][sl];
            }
#pragma unroll
            for (int i = 0; i < 4; ++i) {
                const int rm = wm + (i << 4) + lcol;
                bf16x8 ah = *(const bf16x8*)&As_h[rm][sl];
                bf16x8 al = *(const bf16x8*)&As_l[rm][sl];
#pragma unroll
                for (int j = 0; j < 2; ++j) {
                    acc[i][j] = __builtin_amdgcn_mfma_f32_16x16x32_bf16(ah, bh[j], acc[i][j], 0, 0, 0);
                    acc[i][j] = __builtin_amdgcn_mfma_f32_16x16x32_bf16(al, bh[j], acc[i][j], 0, 0, 0);
                    acc[i][j] = __builtin_amdgcn_mfma_f32_16x16x32_bf16(ah, bl[j], acc[i][j], 0, 0, 0);
                }
            }
        }
    }

    // epilogue: C/D layout row=quad*4+r, col=lcol
#pragma unroll
    for (int j = 0; j < 2; ++j) {
        const int col = bn + wn + (j << 4) + lcol;
        const float bj = bias[col];
#pragma unroll
        for (int i = 0; i < 4; ++i) {
#pragma unroll
            for (int r = 0; r < 4; ++r) {
                const int row = bm + wm + (i << 4) + quad * 4 + r;
                const float v = (acc[i][j][r] + bj) * scale;
                const size_t o = (size_t)row * N + col;
                if (outF) {
                    outF[o] = v;
                } else {
                    u16 hi, lo;
                    split_bf16(v, hi, lo);
                    outH[o] = hi;
                    outL[o] = lo;
                }
            }
        }
    }
}

// ---------------------------------------------------------------------------
// Per-head transpose of V planes: out[b][h][d][n] = in[b][n][h*64+d]
// ---------------------------------------------------------------------------
__global__ __launch_bounds__(256)
void transpose_heads(const u16* __restrict__ inh, const u16* __restrict__ inl,
                     u16* __restrict__ outh, u16* __restrict__ outl)
{
    __shared__ u16 T[64][72];
    const int tid = threadIdx.x;
    const int n0 = blockIdx.x * 64;
    const int h = blockIdx.y, b = blockIdx.z;
    const int lr = tid >> 2, lc = (tid & 3) * 16;
    const size_t ibase = (size_t)(b * NSEQ) * D_MODEL + h * DK;
    const size_t obase = (size_t)(b * NUM_HEADS + h) * DK * NSEQ;
    const u16* src[2] = {inh, inl};
    u16* dst[2] = {outh, outl};
#pragma unroll
    for (int p = 0; p < 2; ++p) {
        __syncthreads();
        const u16* s = src[p] + ibase + (size_t)(n0 + lr) * D_MODEL + lc;
        *(uint4*)&T[lr][lc]     = *(const uint4*)s;
        *(uint4*)&T[lr][lc + 8] = *(const uint4*)(s + 8);
        __syncthreads();
        u16 vals[16];
#pragma unroll
        for (int j = 0; j < 16; ++j) vals[j] = T[lc + j][lr];
        u16* d = dst[p] + obase + (size_t)lr * NSEQ + n0 + lc;
        *(uint4*)d       = *(uint4*)&vals[0];
        *(uint4*)(d + 8) = *(uint4*)&vals[8];
    }
}

// ---------------------------------------------------------------------------
// Flash attention, split-bf16 MFMA. 128 q-rows/block, 4 waves x 32 q-rows
// (2 sets of 16). Q fragments live in registers (loaded once from global).
// K/V tiles staged in LDS; P round-trips through wave-PRIVATE LDS (no barrier).
// 2 barriers/tile. Grid (16,16,2)=512 blocks, 2/CU, LDS 73.7 KB.
// ---------------------------------------------------------------------------
__global__ __launch_bounds__(256)
void flash_attn_mfma(const u16* __restrict__ Qh_g, const u16* __restrict__ Ql_g,
                     const u16* __restrict__ Kh_g, const u16* __restrict__ Kl_g,
                     const u16* __restrict__ Vth_g, const u16* __restrict__ Vtl_g,
                     u16* __restrict__ Ch_g, u16* __restrict__ Cl_g)
{
    __shared__ __align__(16) u16 Ks_h[64][72], Ks_l[64][72];
    __shared__ __align__(16) u16 Vs_h[64][72], Vs_l[64][72];   // [d][key]
    __shared__ __align__(16) u16 Ps_h[4][32][72], Ps_l[4][32][72];

    const int tid  = threadIdx.x;
    const int wv   = tid >> 6;
    const int lane = tid & 63;
    const int quad = lane >> 4;
    const int lcol = lane & 15;
    const int q0   = blockIdx.x << 7;   // 128 q rows per block
    const int h    = blockIdx.y;
    const int b    = blockIdx.z;
    const size_t hbase  = (size_t)b * NSEQ * D_MODEL + (size_t)h * DK;
    const size_t vtbase = (size_t)(b * NUM_HEADS + h) * DK * NSEQ;

    // Q A-fragments straight from global (one-time, uncoalesced but tiny)
    bf16x8 aQh[2][2], aQl[2][2];
#pragma unroll
    for (int s = 0; s < 2; ++s) {
        const u16* qh = Qh_g + hbase + (size_t)(q0 + wv * 32 + s * 16 + lcol) * D_MODEL;
        const u16* ql = Ql_g + hbase + (size_t)(q0 + wv * 32 + s * 16 + lcol) * D_MODEL;
#pragma unroll
        for (int c = 0; c < 2; ++c) {
            aQh[s][c] = *(const bf16x8*)(qh + c * 32 + quad * 8);
            aQl[s][c] = *(const bf16x8*)(ql + c * 32 + quad * 8);
        }
    }

    f32x4 Oacc[2][4];
    float mrow[2][4], lrow[2][4], alpha[2][4];
#pragma unroll
    for (int s = 0; s < 2; ++s) {
#pragma unroll
        for (int t = 0; t < 4; ++t) Oacc[s][t] = (f32x4){0.f, 0.f, 0.f, 0.f};
#pragma unroll
        for (int r = 0; r < 4; ++r) { mrow[s][r] = -INFINITY; lrow[s][r] = 0.f; }
    }

    const int lr = tid >> 2;           // staging row 0..63
    const int lc = (tid & 3) << 4;     // staging col group (16 u16)

    for (int kt = 0; kt < NSEQ / 64; ++kt) {
        const int k0 = kt << 6;
        __syncthreads();   // all waves done reading previous K/V
        {   // stage K [key][d] and Vt [d][key], both planes — pure copies
            const u16* skh = Kh_g + hbase + (size_t)(k0 + lr) * D_MODEL + lc;
            const u16* skl = Kl_g + hbase + (size_t)(k0 + lr) * D_MODEL + lc;
            const u16* svh = Vth_g + vtbase + (size_t)lr * NSEQ + k0 + lc;
            const u16* svl = Vtl_g + vtbase + (size_t)lr * NSEQ + k0 + lc;
            *(uint4*)&Ks_h[lr][lc]     = *(const uint4*)skh;
            *(uint4*)&Ks_h[lr][lc + 8] = *(const uint4*)(skh + 8);
            *(uint4*)&Ks_l[lr][lc]     = *(const uint4*)skl;
            *(uint4*)&Ks_l[lr][lc + 8] = *(const uint4*)(skl + 8);
            *(uint4*)&Vs_h[lr][lc]     = *(const uint4*)svh;
            *(uint4*)&Vs_h[lr][lc + 8] = *(const uint4*)(svh + 8);
            *(uint4*)&Vs_l[lr][lc]     = *(const uint4*)svl;
            *(uint4*)&Vs_l[lr][lc + 8] = *(const uint4*)(svl + 8);
        }
        __syncthreads();

        // S = Q K^T: K-fragments shared across both q-sets
        f32x4 S[2][4];
#pragma unroll
        for (int t = 0; t < 4; ++t) {
            bf16x8 bKh0 = *(const bf16x8*)&Ks_h[(t << 4) + lcol][quad * 8];
            bf16x8 bKh1 = *(const bf16x8*)&Ks_h[(t << 4) + lcol][32 + quad * 8];
            bf16x8 bKl0 = *(const bf16x8*)&Ks_l[(t << 4) + lcol][quad * 8];
            bf16x8 bKl1 = *(const bf16x8*)&Ks_l[(t << 4) + lcol][32 + quad * 8];
#pragma unroll
            for (int s = 0; s < 2; ++s) {
                f32x4 a = (f32x4){0.f, 0.f, 0.f, 0.f};
                a = __builtin_amdgcn_mfma_f32_16x16x32_bf16(aQh[s][0], bKh0, a, 0, 0, 0);
                a = __builtin_amdgcn_mfma_f32_16x16x32_bf16(aQh[s][1], bKh1, a, 0, 0, 0);
                a = __builtin_amdgcn_mfma_f32_16x16x32_bf16(aQl[s][0], bKh0, a, 0, 0, 0);
                a = __builtin_amdgcn_mfma_f32_16x16x32_bf16(aQl[s][1], bKh1, a, 0, 0, 0);
                a = __builtin_amdgcn_mfma_f32_16x16x32_bf16(aQh[s][0], bKl0, a, 0, 0, 0);
                a = __builtin_amdgcn_mfma_f32_16x16x32_bf16(aQh[s][1], bKl1, a, 0, 0, 0);
                S[s][t] = a;
            }
        }

        // online softmax per set (register + shfl over the 16 key-lanes)
#pragma unroll
        for (int s = 0; s < 2; ++s) {
            float rmax[4];
#pragma unroll
            for (int r = 0; r < 4; ++r)
                rmax[r] = fmaxf(fmaxf(S[s][0][r], S[s][1][r]), fmaxf(S[s][2][r], S[s][3][r]));
#pragma unroll
            for (int off = 1; off < 16; off <<= 1)
#pragma unroll
                for (int r = 0; r < 4; ++r)
                    rmax[r] = fmaxf(rmax[r], __shfl_xor(rmax[r], off, 64));
#pragma unroll
            for (int r = 0; r < 4; ++r) {
                float mn = fmaxf(mrow[s][r], rmax[r]);
                alpha[s][r] = __expf(mrow[s][r] - mn);
                mrow[s][r] = mn;
            }
            float psum[4] = {0.f, 0.f, 0.f, 0.f};
#pragma unroll
            for (int t = 0; t < 4; ++t)
#pragma unroll
                for (int r = 0; r < 4; ++r) {
                    float pv = __expf(S[s][t][r] - mrow[s][r]);
                    psum[r] += pv;
                    u16 hi, lo;
                    split_bf16(pv, hi, lo);
                    Ps_h[wv][s * 16 + quad * 4 + r][(t << 4) + lcol] = hi;
                    Ps_l[wv][s * 16 + quad * 4 + r][(t << 4) + lcol] = lo;
                }
#pragma unroll
            for (int off = 1; off < 16; off <<= 1)
#pragma unroll
                for (int r = 0; r < 4; ++r)
                    psum[r] += __shfl_xor(psum[r], off, 64);
#pragma unroll
            for (int r = 0; r < 4; ++r)
                lrow[s][r] = alpha[s][r] * lrow[s][r] + psum[r];
        }
        // NO __syncthreads: P region is wave-private; lgkmcnt ordering suffices.

        bf16x8 aPh[2][2], aPl[2][2];
#pragma unroll
        for (int s = 0; s < 2; ++s)
#pragma unroll
            for (int c = 0; c < 2; ++c) {
                aPh[s][c] = *(const bf16x8*)&Ps_h[wv][s * 16 + lcol][c * 32 + quad * 8];
                aPl[s][c] = *(const bf16x8*)&Ps_l[wv][s * 16 + lcol][c * 32 + quad * 8];
            }

        // O = O*alpha + P V: V-fragments shared across both q-sets
#pragma unroll
        for (int t = 0; t < 4; ++t) {
            bf16x8 bVh0 = *(const bf16x8*)&Vs_h[(t << 4) + lcol][quad * 8];
            bf16x8 bVh1 = *(const bf16x8*)&Vs_h[(t << 4) + lcol][32 + quad * 8];
            bf16x8 bVl0 = *(const bf16x8*)&Vs_l[(t << 4) + lcol][quad * 8];
            bf16x8 bVl1 = *(const bf16x8*)&Vs_l[(t << 4) + lcol][32 + quad * 8];
#pragma unroll
            for (int s = 0; s < 2; ++s) {
                f32x4 o = Oacc[s][t];
#pragma unroll
                for (int r = 0; r < 4; ++r) o[r] *= alpha[s][r];
                o = __builtin_amdgcn_mfma_f32_16x16x32_bf16(aPh[s][0], bVh0, o, 0, 0, 0);
                o = __builtin_amdgcn_mfma_f32_16x16x32_bf16(aPh[s][1], bVh1, o, 0, 0, 0);
                o = __builtin_amdgcn_mfma_f32_16x16x32_bf16(aPl[s][0], bVh0, o, 0, 0, 0);
                o = __builtin_amdgcn_mfma_f32_16x16x32_bf16(aPl[s][1], bVh1, o, 0, 0, 0);
                o = __builtin_amdgcn_mfma_f32_16x16x32_bf16(aPh[s][0], bVl0, o, 0, 0, 0);
                o = __builtin_amdgcn_mfma_f32_16x16x32_bf16(aPh[s][1], bVl1, o, 0, 0, 0);
                Oacc[s][t] = o;
            }
        }
    }

    // epilogue: normalize, split, store ctx planes
#pragma unroll
    for (int s = 0; s < 2; ++s) {
        float inv[4];
#pragma unroll
        for (int r = 0; r < 4; ++r) inv[r] = 1.f / lrow[s][r];
        const size_t rowbase = hbase + (size_t)(q0 + wv * 32 + s * 16) * D_MODEL;
#pragma unroll
        for (int t = 0; t < 4; ++t)
#pragma unroll
            for (int r = 0; r < 4; ++r) {
                u16 hi, lo;
                split_bf16(Oacc[s][t][r] * inv[r], hi, lo);
                const size_t o = rowbase + (size_t)(quad * 4 + r) * D_MODEL + (t << 4) + lcol;
                Ch_g[o] = hi;
                Cl_g[o] = lo;
            }
    }
}

// ---------------------------------------------------------------------------
extern "C" void kernel_launch(void* const* d_in, const int* in_sizes, int n_in,
                              void* d_out, int out_size, void* d_ws, size_t ws_size,
                              hipStream_t stream)
{
    const float* query = (const float*)d_in[0];
    const float* key_i = (const float*)d_in[1];
    const float* value = (const float*)d_in[2];
    const float* w_q   = (const float*)d_in[3];
    const float* b_q   = (const float*)d_in[4];
    const float* w_k   = (const float*)d_in[5];
    const float* b_k   = (const float*)d_in[6];
    const float* w_v   = (const float*)d_in[7];
    const float* b_v   = (const float*)d_in[8];
    const float* w_o   = (const float*)d_in[9];
    const float* b_o   = (const float*)d_in[10];
    float* out = (float*)d_out;

    const size_t WE = (size_t)D_MODEL * D_MODEL;   // 1M elems per weight
    const size_t AE = (size_t)MROWS * D_MODEL;     // 4M elems per activation

    u16* p = (u16*)d_ws;
    u16* Wqh = p;            u16* Wql = Wqh + WE;
    u16* Wkh = Wql + WE;     u16* Wkl = Wkh + WE;
    u16* Wvh = Wkl + WE;     u16* Wvl = Wvh + WE;
    u16* Woh = Wvl + WE;     u16* Wol = Woh + WE;
    u16* INh = Wol + WE;     u16* INl = INh + AE;
    u16* VTh = INh;          u16* VTl = INl;        // alias (IN dead after V GEMM)
    u16* Qh = INl + AE;      u16* Ql = Qh + AE;
    u16* Kh = Ql + AE;       u16* Kl = Kh + AE;
    u16* Vh = Kl + AE;       u16* Vl = Vh + AE;
    u16* Ch = Vh;            u16* Cl = Vl;          // alias (V dead after transpose)
    // total: 80 MB

    // fused weight splits
    SplitArgs sa;
    sa.src[0] = w_q; sa.h[0] = Wqh; sa.l[0] = Wql;
    sa.src[1] = w_k; sa.h[1] = Wkh; sa.l[1] = Wkl;
    sa.src[2] = w_v; sa.h[2] = Wvh; sa.l[2] = Wvl;
    sa.src[3] = w_o; sa.h[3] = Woh; sa.l[3] = Wol;
    dim3 wsplit((int)(WE / 8 / 256), 4);
    split_f32_multi<<<wsplit, 256, 0, stream>>>(sa, (int)(WE / 8));

    const int agrid = (int)(AE / 8 / 256);   // 2048
    dim3 ggrid(D_MODEL / GBN, MROWS / GBM);  // (16, 32)

    split_f32<<<agrid, 256, 0, stream>>>(query, INh, INl, (int)(AE / 8));
    gemm_mfma_split<<<ggrid, 256, 0, stream>>>(INh, INl, Wqh, Wql, b_q,
                                               nullptr, Qh, Ql, 0.125f,
                                               MROWS, D_MODEL, D_MODEL);
    split_f32<<<agrid, 256, 0, stream>>>(key_i, INh, INl, (int)(AE / 8));
    gemm_mfma_split<<<ggrid, 256, 0, stream>>>(INh, INl, Wkh, Wkl, b_k,
                                               nullptr, Kh, Kl, 1.0f,
                                               MROWS, D_MODEL, D_MODEL);
    split_f32<<<agrid, 256, 0, stream>>>(value, INh, INl, (int)(AE / 8));
    gemm_mfma_split<<<ggrid, 256, 0, stream>>>(INh, INl, Wvh, Wvl, b_v,
                                               nullptr, Vh, Vl, 1.0f,
                                               MROWS, D_MODEL, D_MODEL);

    dim3 tgrid(NSEQ / 64, NUM_HEADS, BATCH);
    transpose_heads<<<tgrid, 256, 0, stream>>>(Vh, Vl, VTh, VTl);

    dim3 fgrid(NSEQ / 128, NUM_HEADS, BATCH);   // (16, 16, 2)
    flash_attn_mfma<<<fgrid, 256, 0, stream>>>(Qh, Ql, Kh, Kl, VTh, VTl, Ch, Cl);

    gemm_mfma_split<<<ggrid, 256, 0, stream>>>(Ch, Cl, Woh, Wol, b_o,
                                               out, nullptr, nullptr, 1.0f,
                                               MROWS, D_MODEL, D_MODEL);
}

// Round 5
// 339.173 us; speedup vs baseline: 6.0536x; 1.3159x over previous
//
#include <hip/hip_runtime.h>
#include <math.h>

#define D_MODEL 1024
#define NUM_HEADS 16
#define DK 64
#define BATCH 2
#define NSEQ 2048
#define MROWS (BATCH * NSEQ)   // 4096

typedef __attribute__((ext_vector_type(8))) short bf16x8;
typedef __attribute__((ext_vector_type(4))) short s16x4;
typedef __attribute__((ext_vector_type(4))) float f32x4;
typedef unsigned short u16;

// round-to-nearest-even fp32 -> bf16 bits
static __device__ __forceinline__ u16 f2bf_rne(float x) {
    union { float f; unsigned u; } v; v.f = x;
    unsigned r = v.u + 0x7fffu + ((v.u >> 16) & 1u);
    return (u16)(r >> 16);
}
// split x = hi + lo; hi = truncated-bf16, lo = RNE bf16 of remainder.
static __device__ __forceinline__ void split_bf16(float x, u16& hi, u16& lo) {
    union { float f; unsigned u; } v; v.f = x;
    unsigned hb = v.u & 0xffff0000u;
    hi = (u16)(hb >> 16);
    union { unsigned u; float f; } hv; hv.u = hb;
    lo = f2bf_rne(x - hv.f);
}

#define AS1 __attribute__((address_space(1)))
#define AS3 __attribute__((address_space(3)))
static __device__ __forceinline__ void gl_lds16(const void* g, void* l) {
    __builtin_amdgcn_global_load_lds((AS1 void*)(uintptr_t)g, (AS3 void*)l, 16, 0, 0);
}

// ---------------------------------------------------------------------------
// fp32 -> split bf16 planes, up to 4 tensors in one launch (blockIdx.y).
// ---------------------------------------------------------------------------
struct SplitN { const float* src[4]; u16* h[4]; u16* l[4]; };
__global__ __launch_bounds__(256)
void split_multi(SplitN args, int n8)
{
    const int w = blockIdx.y;
    const int i = blockIdx.x * 256 + threadIdx.x;
    if (i >= n8) return;
    const float* src = args.src[w];
    float4 a = ((const float4*)src)[2 * i];
    float4 b = ((const float4*)src)[2 * i + 1];
    float x[8] = {a.x, a.y, a.z, a.w, b.x, b.y, b.z, b.w};
    u16 hh[8], ll[8];
#pragma unroll
    for (int j = 0; j < 8; ++j) split_bf16(x[j], hh[j], ll[j]);
    *(uint4*)(args.h[w] + 8 * (size_t)i) = *(uint4*)hh;
    *(uint4*)(args.l[w] + 8 * (size_t)i) = *(uint4*)ll;
}

// ---------------------------------------------------------------------------
// Batched MFMA GEMM, split-bf16 3-term: C = (A @ W^T + bias) * scale.
// BM=128 BN=64 BK=64, 256 thr (4 waves 2x2), 16B-granule XOR swizzle staging.
// mode 0: fp32 out. mode 1: split-plane out. mode 2: V path — single RNE
// plane written per-head TRANSPOSED ([b][h][d][n]) via LDS re-transpose.
// blockIdx.z selects descriptor.
// ---------------------------------------------------------------------------
#define GBM 128
#define GBN 64
#define GBK 64

struct GemmDesc {
    const u16 *Ah, *Al, *Wh, *Wl;
    const float* bias;
    float* outF;
    u16 *outH, *outL;
    float scale;
    int mode;
};
struct GemmBatch { GemmDesc d[3]; };

__global__ __launch_bounds__(256)
void gemm_mfma_batch(GemmBatch batch, int M, int N, int K)
{
    __shared__ u16 SM[2 * GBM * GBK + 2 * GBN * GBK];   // 48 KB pool
    u16* As_h = SM;                       // [128][64]
    u16* As_l = SM + GBM * GBK;
    u16* Ws_h = SM + 2 * GBM * GBK;       // [64][64]
    u16* Ws_l = SM + 2 * GBM * GBK + GBN * GBK;

    const GemmDesc d = batch.d[blockIdx.z];
    const int tid  = threadIdx.x;
    const int wv   = tid >> 6, lane = tid & 63;
    const int quad = lane >> 4, lcol = lane & 15;
    const int bm = blockIdx.y * GBM, bn = blockIdx.x * GBN;
    const int wm = (wv >> 1) * 64, wn = (wv & 1) * 32;
    const int sj = lane >> 3, sg = lane & 7;
    const int sgx8 = ((sg ^ sj) << 3);

    f32x4 acc[4][2];
#pragma unroll
    for (int i = 0; i < 4; ++i)
#pragma unroll
        for (int j = 0; j < 2; ++j) acc[i][j] = (f32x4){0.f, 0.f, 0.f, 0.f};

    for (int k0 = 0; k0 < K; k0 += GBK) {
        __syncthreads();
#pragma unroll
        for (int c = 0; c < 4; ++c) {
            const int r0 = wv * 32 + c * 8;
            gl_lds16(d.Ah + (size_t)(bm + r0 + sj) * K + k0 + sgx8, As_h + r0 * GBK);
            gl_lds16(d.Al + (size_t)(bm + r0 + sj) * K + k0 + sgx8, As_l + r0 * GBK);
        }
#pragma unroll
        for (int c = 0; c < 2; ++c) {
            const int r0 = wv * 16 + c * 8;
            gl_lds16(d.Wh + (size_t)(bn + r0 + sj) * K + k0 + sgx8, Ws_h + r0 * GBK);
            gl_lds16(d.Wl + (size_t)(bn + r0 + sj) * K + k0 + sgx8, Ws_l + r0 * GBK);
        }
        __syncthreads();

#pragma unroll
        for (int hf = 0; hf < 2; ++hf) {
            const int sl = ((((hf << 2) + quad) ^ (lcol & 7)) << 3);
            bf16x8 bh[2], bl[2];
#pragma unroll
            for (int j = 0; j < 2; ++j) {
                const int rn = wn + (j << 4) + lcol;
                bh[j] = *(const bf16x8*)(Ws_h + rn * GBK + sl);
                bl[j] = *(const bf16x8*)(Ws_l + rn * GBK + sl);
            }
#pragma unroll
            for (int i = 0; i < 4; ++i) {
                const int rm = wm + (i << 4) + lcol;
                bf16x8 ah = *(const bf16x8*)(As_h + rm * GBK + sl);
                bf16x8 al = *(const bf16x8*)(As_l + rm * GBK + sl);
#pragma unroll
                for (int j = 0; j < 2; ++j) {
                    acc[i][j] = __builtin_amdgcn_mfma_f32_16x16x32_bf16(ah, bh[j], acc[i][j], 0, 0, 0);
                    acc[i][j] = __builtin_amdgcn_mfma_f32_16x16x32_bf16(al, bh[j], acc[i][j], 0, 0, 0);
                    acc[i][j] = __builtin_amdgcn_mfma_f32_16x16x32_bf16(ah, bl[j], acc[i][j], 0, 0, 0);
                }
            }
        }
    }

    if (d.mode == 2) {
        // V path: re-transpose via LDS, write Vt[b][h][d][n] single RNE plane.
        const int TS = 136;                 // u16 stride, conflict-benign
        u16* T = SM;                        // 64 x 136 = 17408 u16 <= pool
        __syncthreads();
#pragma unroll
        for (int j = 0; j < 2; ++j) {
            const int cl = wn + (j << 4) + lcol;       // d-local 0..63
            const float bj = d.bias[bn + cl];
#pragma unroll
            for (int i = 0; i < 4; ++i) {
                const int r0 = wm + (i << 4) + quad * 4;   // n-local, mult of 4
                u16 pk[4];
#pragma unroll
                for (int r = 0; r < 4; ++r) pk[r] = f2bf_rne(acc[i][j][r] + bj);
                *(ushort4*)(T + cl * TS + r0) = *(ushort4*)pk;
            }
        }
        __syncthreads();
        const int dd = tid >> 2, pt = tid & 3;
        const int bidx = bm >> 11, hh = bn >> 6;
        u16* dst = d.outH + ((size_t)(bidx * NUM_HEADS + hh) * DK + dd) * NSEQ
                 + (bm & (NSEQ - 1)) + pt * 32;
        const u16* src = T + dd * TS + pt * 32;
#pragma unroll
        for (int k = 0; k < 4; ++k)
            ((uint4*)dst)[k] = *(const uint4*)(src + 8 * k);
        return;
    }

#pragma unroll
    for (int j = 0; j < 2; ++j) {
        const int col = bn + wn + (j << 4) + lcol;
        const float bj = d.bias[col];
#pragma unroll
        for (int i = 0; i < 4; ++i) {
#pragma unroll
            for (int r = 0; r < 4; ++r) {
                const int row = bm + wm + (i << 4) + quad * 4 + r;
                const float v = (acc[i][j][r] + bj) * d.scale;
                const size_t o = (size_t)row * N + col;
                if (d.mode == 0) {
                    d.outF[o] = v;
                } else {
                    u16 hi, lo;
                    split_bf16(v, hi, lo);
                    d.outH[o] = hi;
                    d.outL[o] = lo;
                }
            }
        }
    }
}

// ---------------------------------------------------------------------------
// Flash attention. 128 q/block, 4 waves x (2 sets of 16 q).
// S^T = K·Q^T via MFMA(A=K-frag from LDS, B=Q-frag regs): C-layout q=lcol.
// Softmax per-lane + 2 shfl_xor. P^T C-regs feed PV directly as B-frags of
// 16x16x32 MFMAs under the quad-consistent k-permutation
//   k=8*quad+4*tau+r  <->  key=32c+16*tau+4*quad+r
// with A = V^T frags (ds_read_b64 from Vt[d][key], single RNE plane).
// O^T[d][q]: col=q=lcol -> per-lane alpha & 1/l. No P LDS, 2 barriers/tile.
// LDS 27.6 KB.
// ---------------------------------------------------------------------------
__global__ __launch_bounds__(256)
void flash_attn(const u16* __restrict__ Qh_g, const u16* __restrict__ Ql_g,
                const u16* __restrict__ Kh_g, const u16* __restrict__ Kl_g,
                const u16* __restrict__ Vt_g,
                u16* __restrict__ Ch_g, u16* __restrict__ Cl_g)
{
    __shared__ __align__(16) u16 Ks_h[64][72], Ks_l[64][72];
    __shared__ __align__(16) u16 Vs[64][72];    // [d][key]

    const int tid  = threadIdx.x;
    const int wv   = tid >> 6;
    const int lane = tid & 63;
    const int quad = lane >> 4;
    const int lcol = lane & 15;
    const int q0   = blockIdx.x << 7;
    const int h    = blockIdx.y;
    const int b    = blockIdx.z;
    const size_t hbase  = (size_t)b * NSEQ * D_MODEL + (size_t)h * DK;
    const size_t vtbase = (size_t)(b * NUM_HEADS + h) * DK * NSEQ;

    // Q B-fragments from global: B[k=d=quad*8+j][n=q=lcol]
    bf16x8 bQh[2][2], bQl[2][2];
#pragma unroll
    for (int s = 0; s < 2; ++s) {
        const u16* qh = Qh_g + hbase + (size_t)(q0 + wv * 32 + s * 16 + lcol) * D_MODEL;
        const u16* ql = Ql_g + hbase + (size_t)(q0 + wv * 32 + s * 16 + lcol) * D_MODEL;
#pragma unroll
        for (int c = 0; c < 2; ++c) {
            bQh[s][c] = *(const bf16x8*)(qh + c * 32 + quad * 8);
            bQl[s][c] = *(const bf16x8*)(ql + c * 32 + quad * 8);
        }
    }

    f32x4 Oacc[2][4];   // [set][dt]: O^T rows d=16dt+quad*4+r, col q=lcol
#pragma unroll
    for (int s = 0; s < 2; ++s)
#pragma unroll
        for (int t = 0; t < 4; ++t) Oacc[s][t] = (f32x4){0.f, 0.f, 0.f, 0.f};
    float mrow[2] = {-INFINITY, -INFINITY};
    float lrow[2] = {0.f, 0.f};

    const int lr = tid >> 2;           // staging row 0..63
    const int lc = (tid & 3) << 4;     // staging col group (16 u16)

    for (int kt = 0; kt < NSEQ / 64; ++kt) {
        const int k0 = kt << 6;
        __syncthreads();
        {
            const u16* skh = Kh_g + hbase + (size_t)(k0 + lr) * D_MODEL + lc;
            const u16* skl = Kl_g + hbase + (size_t)(k0 + lr) * D_MODEL + lc;
            const u16* sv  = Vt_g + vtbase + (size_t)lr * NSEQ + k0 + lc;
            *(uint4*)&Ks_h[lr][lc]     = *(const uint4*)skh;
            *(uint4*)&Ks_h[lr][lc + 8] = *(const uint4*)(skh + 8);
            *(uint4*)&Ks_l[lr][lc]     = *(const uint4*)skl;
            *(uint4*)&Ks_l[lr][lc + 8] = *(const uint4*)(skl + 8);
            *(uint4*)&Vs[lr][lc]       = *(const uint4*)sv;
            *(uint4*)&Vs[lr][lc + 8]   = *(const uint4*)(sv + 8);
        }
        __syncthreads();

        // S^T[key][q] = K·Q^T, 3-term split (Kh·Qh + Kl·Qh + Kh·Ql)
        f32x4 S[2][4];
#pragma unroll
        for (int t = 0; t < 4; ++t) {
            bf16x8 aKh0 = *(const bf16x8*)&Ks_h[(t << 4) + lcol][quad * 8];
            bf16x8 aKh1 = *(const bf16x8*)&Ks_h[(t << 4) + lcol][32 + quad * 8];
            bf16x8 aKl0 = *(const bf16x8*)&Ks_l[(t << 4) + lcol][quad * 8];
            bf16x8 aKl1 = *(const bf16x8*)&Ks_l[(t << 4) + lcol][32 + quad * 8];
#pragma unroll
            for (int s = 0; s < 2; ++s) {
                f32x4 a = (f32x4){0.f, 0.f, 0.f, 0.f};
                a = __builtin_amdgcn_mfma_f32_16x16x32_bf16(aKh0, bQh[s][0], a, 0, 0, 0);
                a = __builtin_amdgcn_mfma_f32_16x16x32_bf16(aKh1, bQh[s][1], a, 0, 0, 0);
                a = __builtin_amdgcn_mfma_f32_16x16x32_bf16(aKl0, bQh[s][0], a, 0, 0, 0);
                a = __builtin_amdgcn_mfma_f32_16x16x32_bf16(aKl1, bQh[s][1], a, 0, 0, 0);
                a = __builtin_amdgcn_mfma_f32_16x16x32_bf16(aKh0, bQl[s][0], a, 0, 0, 0);
                a = __builtin_amdgcn_mfma_f32_16x16x32_bf16(aKh1, bQl[s][1], a, 0, 0, 0);
                S[s][t] = a;
            }
        }

        // softmax + P packing (per lane: 16 keys for q=lcol)
        bf16x8 pb[2][2];   // [set][c]: j=4*tau+r -> p[2c+tau][r]
#pragma unroll
        for (int s = 0; s < 2; ++s) {
            float m16 = -INFINITY;
#pragma unroll
            for (int t = 0; t < 4; ++t)
#pragma unroll
                for (int r = 0; r < 4; ++r) m16 = fmaxf(m16, S[s][t][r]);
            m16 = fmaxf(m16, __shfl_xor(m16, 16, 64));
            m16 = fmaxf(m16, __shfl_xor(m16, 32, 64));
            const float mn = fmaxf(mrow[s], m16);
            const float alpha = __expf(mrow[s] - mn);
            mrow[s] = mn;

            float p[4][4];
            float psum = 0.f;
#pragma unroll
            for (int t = 0; t < 4; ++t)
#pragma unroll
                for (int r = 0; r < 4; ++r) {
                    const float pv = __expf(S[s][t][r] - mn);
                    p[t][r] = pv;
                    psum += pv;
                }
            psum += __shfl_xor(psum, 16, 64);
            psum += __shfl_xor(psum, 32, 64);
            lrow[s] = alpha * lrow[s] + psum;

#pragma unroll
            for (int c = 0; c < 2; ++c) {
                bf16x8 v;
#pragma unroll
                for (int r = 0; r < 4; ++r) {
                    v[r]     = (short)f2bf_rne(p[2 * c][r]);
                    v[4 + r] = (short)f2bf_rne(p[2 * c + 1][r]);
                }
                pb[s][c] = v;
            }
#pragma unroll
            for (int t = 0; t < 4; ++t)
#pragma unroll
                for (int r = 0; r < 4; ++r) Oacc[s][t][r] *= alpha;
        }

        // O^T += V^T · P : A = V^T frag (k-permuted), B = pb
#pragma unroll
        for (int dt = 0; dt < 4; ++dt) {
            const u16* vrow = &Vs[(dt << 4) + lcol][0];
#pragma unroll
            for (int c = 0; c < 2; ++c) {
                s16x4 alo = *(const s16x4*)(vrow + c * 32 + quad * 4);        // tau=0
                s16x4 ahi = *(const s16x4*)(vrow + c * 32 + 16 + quad * 4);   // tau=1
                bf16x8 aV;
#pragma unroll
                for (int r = 0; r < 4; ++r) { aV[r] = alo[r]; aV[4 + r] = ahi[r]; }
#pragma unroll
                for (int s = 0; s < 2; ++s)
                    Oacc[s][dt] = __builtin_amdgcn_mfma_f32_16x16x32_bf16(aV, pb[s][c], Oacc[s][dt], 0, 0, 0);
            }
        }
    }

    // epilogue: O^T rows d=16dt+4quad+r, col q=lcol; per-lane 1/l
#pragma unroll
    for (int s = 0; s < 2; ++s) {
        const float inv = 1.f / lrow[s];
        const size_t base = hbase + (size_t)(q0 + wv * 32 + s * 16 + lcol) * D_MODEL;
#pragma unroll
        for (int dt = 0; dt < 4; ++dt) {
            u16 hv[4], lv[4];
#pragma unroll
            for (int r = 0; r < 4; ++r)
                split_bf16(Oacc[s][dt][r] * inv, hv[r], lv[r]);
            const size_t o = base + (dt << 4) + quad * 4;
            *(ushort4*)(Ch_g + o) = *(ushort4*)hv;
            *(ushort4*)(Cl_g + o) = *(ushort4*)lv;
        }
    }
}

// ---------------------------------------------------------------------------
extern "C" void kernel_launch(void* const* d_in, const int* in_sizes, int n_in,
                              void* d_out, int out_size, void* d_ws, size_t ws_size,
                              hipStream_t stream)
{
    const float* query = (const float*)d_in[0];
    const float* key_i = (const float*)d_in[1];
    const float* value = (const float*)d_in[2];
    const float* w_q   = (const float*)d_in[3];
    const float* b_q   = (const float*)d_in[4];
    const float* w_k   = (const float*)d_in[5];
    const float* b_k   = (const float*)d_in[6];
    const float* w_v   = (const float*)d_in[7];
    const float* b_v   = (const float*)d_in[8];
    const float* w_o   = (const float*)d_in[9];
    const float* b_o   = (const float*)d_in[10];
    float* out = (float*)d_out;

    const size_t WE = (size_t)D_MODEL * D_MODEL;   // 1M
    const size_t AE = (size_t)MROWS * D_MODEL;     // 4M

    u16* p = (u16*)d_ws;
    u16* Wqh = p;            u16* Wql = Wqh + WE;
    u16* Wkh = Wql + WE;     u16* Wkl = Wkh + WE;
    u16* Wvh = Wkl + WE;     u16* Wvl = Wvh + WE;
    u16* Woh = Wvl + WE;     u16* Wol = Woh + WE;
    u16* base = Wol + WE;

    // weight splits (both paths)
    SplitN ws4;
    ws4.src[0] = w_q; ws4.h[0] = Wqh; ws4.l[0] = Wql;
    ws4.src[1] = w_k; ws4.h[1] = Wkh; ws4.l[1] = Wkl;
    ws4.src[2] = w_v; ws4.h[2] = Wvh; ws4.l[2] = Wvl;
    ws4.src[3] = w_o; ws4.h[3] = Woh; ws4.l[3] = Wol;
    split_multi<<<dim3((unsigned)(WE / 8 / 256), 4), 256, 0, stream>>>(ws4, (int)(WE / 8));

    const float qscale = 0.125f;
    dim3 fgrid(NSEQ / 128, NUM_HEADS, BATCH);       // (16,16,2)
    dim3 ggrid1(D_MODEL / GBN, MROWS / GBM, 1);
    const int an8 = (int)(AE / 8);

    const size_t fused_bytes = 2 * (8 * WE + 11 * AE);   // 104 MB
    if (ws_size >= fused_bytes) {
        // fused path
        u16* INqh = base;          u16* INql = INqh + AE;
        u16* INkh = INql + AE;     u16* INkl = INkh + AE;
        u16* INvh = INkl + AE;     u16* INvl = INvh + AE;
        u16* Qph  = INvl + AE;     u16* Qpl  = Qph + AE;
        u16* Kph  = Qpl + AE;      u16* Kpl  = Kph + AE;
        u16* VT   = Kpl + AE;
        u16* Ch   = INqh;          u16* Cl   = INql;    // alias, dead after QKV

        SplitN as3;
        as3.src[0] = query; as3.h[0] = INqh; as3.l[0] = INql;
        as3.src[1] = key_i; as3.h[1] = INkh; as3.l[1] = INkl;
        as3.src[2] = value; as3.h[2] = INvh; as3.l[2] = INvl;
        as3.src[3] = query; as3.h[3] = INqh; as3.l[3] = INql;  // unused slot
        split_multi<<<dim3((unsigned)(AE / 8 / 256), 3), 256, 0, stream>>>(as3, an8);

        GemmBatch gb;
        gb.d[0] = {INqh, INql, Wqh, Wql, b_q, nullptr, Qph, Qpl, qscale, 1};
        gb.d[1] = {INkh, INkl, Wkh, Wkl, b_k, nullptr, Kph, Kpl, 1.0f,   1};
        gb.d[2] = {INvh, INvl, Wvh, Wvl, b_v, nullptr, VT,  nullptr, 1.0f, 2};
        dim3 ggrid3(D_MODEL / GBN, MROWS / GBM, 3);
        gemm_mfma_batch<<<ggrid3, 256, 0, stream>>>(gb, MROWS, D_MODEL, D_MODEL);

        flash_attn<<<fgrid, 256, 0, stream>>>(Qph, Qpl, Kph, Kpl, VT, Ch, Cl);

        GemmBatch go;
        go.d[0] = {Ch, Cl, Woh, Wol, b_o, out, nullptr, nullptr, 1.0f, 0};
        gemm_mfma_batch<<<ggrid1, 256, 0, stream>>>(go, MROWS, D_MODEL, D_MODEL);
    } else {
        // sequential fallback (72 MB)
        u16* INh = base;           u16* INl = INh + AE;
        u16* Qph = INl + AE;       u16* Qpl = Qph + AE;
        u16* Kph = Qpl + AE;       u16* Kpl = Kph + AE;
        u16* VT  = Kpl + AE;
        u16* Ch  = INh;            u16* Cl  = INl;

        SplitN s1;
        s1.src[0] = query; s1.h[0] = INh; s1.l[0] = INl;
        s1.src[1] = s1.src[2] = s1.src[3] = query;
        s1.h[1] = s1.h[2] = s1.h[3] = INh; s1.l[1] = s1.l[2] = s1.l[3] = INl;

        GemmBatch g;
        s1.src[0] = query;
        split_multi<<<dim3((unsigned)(AE / 8 / 256), 1), 256, 0, stream>>>(s1, an8);
        g.d[0] = {INh, INl, Wqh, Wql, b_q, nullptr, Qph, Qpl, qscale, 1};
        gemm_mfma_batch<<<ggrid1, 256, 0, stream>>>(g, MROWS, D_MODEL, D_MODEL);

        s1.src[0] = key_i;
        split_multi<<<dim3((unsigned)(AE / 8 / 256), 1), 256, 0, stream>>>(s1, an8);
        g.d[0] = {INh, INl, Wkh, Wkl, b_k, nullptr, Kph, Kpl, 1.0f, 1};
        gemm_mfma_batch<<<ggrid1, 256, 0, stream>>>(g, MROWS, D_MODEL, D_MODEL);

        s1.src[0] = value;
        split_multi<<<dim3((unsigned)(AE / 8 / 256), 1), 256, 0, stream>>>(s1, an8);
        g.d[0] = {INh, INl, Wvh, Wvl, b_v, nullptr, VT, nullptr, 1.0f, 2};
        gemm_mfma_batch<<<ggrid1, 256, 0, stream>>>(g, MROWS, D_MODEL, D_MODEL);

        flash_attn<<<fgrid, 256, 0, stream>>>(Qph, Qpl, Kph, Kpl, VT, Ch, Cl);

        g.d[0] = {Ch, Cl, Woh, Wol, b_o, out, nullptr, nullptr, 1.0f, 0};
        gemm_mfma_batch<<<ggrid1, 256, 0, stream>>>(g, MROWS, D_MODEL, D_MODEL);
    }
}